// Round 1
// baseline (366.203 us; speedup 1.0000x reference)
//
#include <hip/hip_runtime.h>
#include <math.h>

// Problem constants (B=16, C=2, H=1024, W=1024)
#define HW   (1024 * 1024)          // H*W = 1M (power of two)
#define NPIX (16 * HW)              // B*H*W = 16,777,216
#define NGRP (NPIX / 4)             // float4 groups over pixel space

__global__ void xy_init_ws(float* ws) {
    ws[0] = 0.0f;
    ws[1] = 0.0f;
}

__device__ __forceinline__ float fast_sigmoid(float x) {
    // 1 / (1 + e^-x); x ~ N(0,1), no overflow concerns
    return __builtin_amdgcn_rcpf(1.0f + __expf(-x));
}

__device__ __forceinline__ float elem_loss(float x0, float x1, float t0, float t1) {
    float p0 = fast_sigmoid(x0);
    float p1 = fast_sigmoid(x1);
    // p0,p1 in (0,1): e^p in (1,e), no need for max-stabilization
    float lse = __logf(__expf(p0) + __expf(p1));
    return (t0 + t1) * lse - (t0 * p0 + t1 * p1);
}

__global__ __launch_bounds__(256) void xy_loss_main(
    const float* __restrict__ mask,   // [B,1,H,W] -> flat pixel index i
    const float* __restrict__ scale,  // [B,1,H,W]
    const float* __restrict__ pred,   // [B,2,H,W] -> base = i + b*HW, +HW for c=1
    const float* __restrict__ truth,  // [B,2,H,W]
    float* __restrict__ ws)
{
    const int tid      = blockIdx.x * blockDim.x + threadIdx.x;
    const int nthreads = gridDim.x * blockDim.x;

    float s1 = 0.0f;  // cross-entropy sum partial
    float s2 = 0.0f;  // mask*scale sum partial

    for (int g = tid; g < NGRP; g += nthreads) {
        const int i    = g << 2;                 // flat pixel index (b*HW + hw)
        const int base = i + (i & ~(HW - 1));    // b*2*HW + hw  (b*HW = i & ~(HW-1))

        const float4 x0 = *(const float4*)(pred  + base);
        const float4 x1 = *(const float4*)(pred  + base + HW);
        const float4 t0 = *(const float4*)(truth + base);
        const float4 t1 = *(const float4*)(truth + base + HW);
        const float4 mk = *(const float4*)(mask  + i);
        const float4 sc = *(const float4*)(scale + i);

        s1 += elem_loss(x0.x, x1.x, t0.x, t1.x);
        s1 += elem_loss(x0.y, x1.y, t0.y, t1.y);
        s1 += elem_loss(x0.z, x1.z, t0.z, t1.z);
        s1 += elem_loss(x0.w, x1.w, t0.w, t1.w);

        s2 += mk.x * sc.x + mk.y * sc.y + mk.z * sc.z + mk.w * sc.w;
    }

    // wave64 shuffle reduction
    #pragma unroll
    for (int off = 32; off > 0; off >>= 1) {
        s1 += __shfl_down(s1, off, 64);
        s2 += __shfl_down(s2, off, 64);
    }

    __shared__ float ls1[4], ls2[4];
    const int lane = threadIdx.x & 63;
    const int wv   = threadIdx.x >> 6;
    if (lane == 0) { ls1[wv] = s1; ls2[wv] = s2; }
    __syncthreads();

    if (threadIdx.x == 0) {
        float a = ls1[0] + ls1[1] + ls1[2] + ls1[3];
        float b = ls2[0] + ls2[1] + ls2[2] + ls2[3];
        atomicAdd(&ws[0], a);   // device-scope by default on CDNA
        atomicAdd(&ws[1], b);
    }
}

__global__ void xy_finalize(const float* __restrict__ ws, float* __restrict__ out) {
    // loss = S1 / NPIX ; out = loss * S2
    out[0] = ws[0] * ws[1] * (1.0f / (float)NPIX);
}

extern "C" void kernel_launch(void* const* d_in, const int* in_sizes, int n_in,
                              void* d_out, int out_size, void* d_ws, size_t ws_size,
                              hipStream_t stream) {
    const float* mask  = (const float*)d_in[0];  // object_mask    [16,1,1024,1024]
    const float* scale = (const float*)d_in[1];  // box_loss_scale [16,1,1024,1024]
    const float* pred  = (const float*)d_in[2];  // predict_xy     [16,2,1024,1024]
    const float* truth = (const float*)d_in[3];  // true_xy        [16,2,1024,1024]
    float* out = (float*)d_out;
    float* ws  = (float*)d_ws;                   // ws[0]=S1, ws[1]=S2 (poisoned 0xAA each call)

    xy_init_ws<<<1, 1, 0, stream>>>(ws);

    // 2048 blocks x 256 threads = 32 waves/CU across 256 CUs (full occupancy)
    xy_loss_main<<<2048, 256, 0, stream>>>(mask, scale, pred, truth, ws);

    xy_finalize<<<1, 1, 0, stream>>>(ws, out);
}

// Round 2
// 360.622 us; speedup vs baseline: 1.0155x; 1.0155x over previous
//
#include <hip/hip_runtime.h>
#include <math.h>

// Problem constants (B=16, C=2, H=1024, W=1024)
#define HW   (1024 * 1024)          // H*W = 1M (power of two)
#define NPIX (16 * HW)              // B*H*W = 16,777,216
#define NGRP (NPIX / 4)             // float4 groups over pixel space

constexpr int THREADS = 256;
constexpr int BLOCKS  = 2048;                 // 8 blocks/CU x 256 CUs
constexpr int NTHR    = THREADS * BLOCKS;     // 524,288
constexpr int ITERS   = NGRP / NTHR;          // 8 (compile-time!)
static_assert(ITERS * NTHR == NGRP, "exact tiling");

struct G6 { float4 x0, x1, t0, t1, mk, sc; };

__device__ __forceinline__ void load_group(
    int g, const float* __restrict__ mask, const float* __restrict__ scale,
    const float* __restrict__ pred, const float* __restrict__ truth, G6& d)
{
    const int i    = g << 2;                 // flat pixel index (b*HW + hw)
    const int base = i + (i & ~(HW - 1));    // b*2*HW + hw
    d.x0 = *(const float4*)(pred  + base);
    d.x1 = *(const float4*)(pred  + base + HW);
    d.t0 = *(const float4*)(truth + base);
    d.t1 = *(const float4*)(truth + base + HW);
    d.mk = *(const float4*)(mask  + i);
    d.sc = *(const float4*)(scale + i);
}

__device__ __forceinline__ float fast_sigmoid(float x) {
    return __builtin_amdgcn_rcpf(1.0f + __expf(-x));
}

__device__ __forceinline__ float elem_loss(float x0, float x1, float t0, float t1) {
    float p0 = fast_sigmoid(x0);
    float p1 = fast_sigmoid(x1);
    // p0,p1 in (0,1): e^p in (1,e), no stabilization needed
    float lse = __logf(__expf(p0) + __expf(p1));
    return (t0 + t1) * lse - (t0 * p0 + t1 * p1);
}

__device__ __forceinline__ void accum_group(const G6& d, float& s1, float& s2) {
    s1 += elem_loss(d.x0.x, d.x1.x, d.t0.x, d.t1.x);
    s1 += elem_loss(d.x0.y, d.x1.y, d.t0.y, d.t1.y);
    s1 += elem_loss(d.x0.z, d.x1.z, d.t0.z, d.t1.z);
    s1 += elem_loss(d.x0.w, d.x1.w, d.t0.w, d.t1.w);
    s2 += d.mk.x * d.sc.x + d.mk.y * d.sc.y + d.mk.z * d.sc.z + d.mk.w * d.sc.w;
}

__global__ __launch_bounds__(THREADS) void xy_loss_main(
    const float* __restrict__ mask,   // [B,1,H,W]
    const float* __restrict__ scale,  // [B,1,H,W]
    const float* __restrict__ pred,   // [B,2,H,W]
    const float* __restrict__ truth,  // [B,2,H,W]
    float* __restrict__ ws)           // [0..BLOCKS): S1 parts, [BLOCKS..2*BLOCKS): S2 parts
{
    int g = blockIdx.x * THREADS + threadIdx.x;

    float s1 = 0.0f, s2 = 0.0f;

    G6 cur, nxt;
    load_group(g, mask, scale, pred, truth, cur);

    #pragma unroll
    for (int it = 0; it < ITERS; ++it) {
        if (it + 1 < ITERS)
            load_group(g + NTHR, mask, scale, pred, truth, nxt);  // prefetch next
        accum_group(cur, s1, s2);                                 // compute current
        cur = nxt;            // register rename under full unroll
        g  += NTHR;
    }

    // wave64 shuffle reduction
    #pragma unroll
    for (int off = 32; off > 0; off >>= 1) {
        s1 += __shfl_down(s1, off, 64);
        s2 += __shfl_down(s2, off, 64);
    }

    __shared__ float ls1[4], ls2[4];
    const int lane = threadIdx.x & 63;
    const int wv   = threadIdx.x >> 6;
    if (lane == 0) { ls1[wv] = s1; ls2[wv] = s2; }
    __syncthreads();

    if (threadIdx.x == 0) {
        ws[blockIdx.x]          = ls1[0] + ls1[1] + ls1[2] + ls1[3];
        ws[BLOCKS + blockIdx.x] = ls2[0] + ls2[1] + ls2[2] + ls2[3];
    }
}

__global__ __launch_bounds__(256) void xy_finalize(
    const float* __restrict__ ws, float* __restrict__ out)
{
    float a = 0.0f, b = 0.0f;
    for (int i = threadIdx.x; i < BLOCKS; i += 256) {
        a += ws[i];
        b += ws[BLOCKS + i];
    }
    #pragma unroll
    for (int off = 32; off > 0; off >>= 1) {
        a += __shfl_down(a, off, 64);
        b += __shfl_down(b, off, 64);
    }
    __shared__ float la[4], lb[4];
    const int lane = threadIdx.x & 63;
    const int wv   = threadIdx.x >> 6;
    if (lane == 0) { la[wv] = a; lb[wv] = b; }
    __syncthreads();
    if (threadIdx.x == 0) {
        float s1 = la[0] + la[1] + la[2] + la[3];
        float s2 = lb[0] + lb[1] + lb[2] + lb[3];
        out[0] = s1 * s2 * (1.0f / (float)NPIX);
    }
}

extern "C" void kernel_launch(void* const* d_in, const int* in_sizes, int n_in,
                              void* d_out, int out_size, void* d_ws, size_t ws_size,
                              hipStream_t stream) {
    const float* mask  = (const float*)d_in[0];  // object_mask    [16,1,1024,1024]
    const float* scale = (const float*)d_in[1];  // box_loss_scale [16,1,1024,1024]
    const float* pred  = (const float*)d_in[2];  // predict_xy     [16,2,1024,1024]
    const float* truth = (const float*)d_in[3];  // true_xy        [16,2,1024,1024]
    float* out = (float*)d_out;
    float* ws  = (float*)d_ws;                   // block partials (written before read)

    xy_loss_main<<<BLOCKS, THREADS, 0, stream>>>(mask, scale, pred, truth, ws);
    xy_finalize<<<1, 256, 0, stream>>>(ws, out);
}

// Round 3
// 355.962 us; speedup vs baseline: 1.0288x; 1.0131x over previous
//
#include <hip/hip_runtime.h>
#include <math.h>

// Problem constants (B=16, C=2, H=1024, W=1024)
#define HW   (1024 * 1024)          // H*W = 1M (power of two)
#define NPIX (16 * HW)              // B*H*W = 16,777,216
#define NGRP (NPIX / 4)             // float4 groups over pixel space = 4,194,304

constexpr int THREADS = 256;
constexpr int BLOCKS  = 1024;                 // 4 blocks/CU x 256 CUs -> 16 waves/CU at VGPR<=128
constexpr int NTHR    = THREADS * BLOCKS;     // 262,144
constexpr int GPT     = NGRP / NTHR;          // 16 groups per thread
constexpr int UNROLL  = 4;                    // groups batched per macro-iteration
constexpr int MACRO   = GPT / UNROLL;         // 4 macro-iterations
static_assert(GPT * NTHR == NGRP, "exact tiling");
static_assert(MACRO * UNROLL == GPT, "exact unroll");

__device__ __forceinline__ float fast_sigmoid(float x) {
    return __builtin_amdgcn_rcpf(1.0f + __expf(-x));
}

__device__ __forceinline__ float elem_loss(float x0, float x1, float t0, float t1) {
    float p0 = fast_sigmoid(x0);
    float p1 = fast_sigmoid(x1);
    // p0,p1 in (0,1): e^p in (1,e), no stabilization needed
    float lse = __logf(__expf(p0) + __expf(p1));
    return (t0 + t1) * lse - (t0 * p0 + t1 * p1);
}

__global__ __launch_bounds__(THREADS, 4) void xy_loss_main(
    const float* __restrict__ mask,   // [B,1,H,W]
    const float* __restrict__ scale,  // [B,1,H,W]
    const float* __restrict__ pred,   // [B,2,H,W]
    const float* __restrict__ truth,  // [B,2,H,W]
    float* __restrict__ ws)           // [0..BLOCKS): S1 parts, [BLOCKS..2*BLOCKS): S2 parts
{
    const int g0 = blockIdx.x * THREADS + threadIdx.x;

    float s1 = 0.0f, s2 = 0.0f;

    #pragma unroll
    for (int m = 0; m < MACRO; ++m) {
        // ---- Phase 1: issue ALL 24 loads for this macro-iteration ----
        float4 x0[UNROLL], x1[UNROLL], t0[UNROLL], t1[UNROLL], mk[UNROLL], sc[UNROLL];
        #pragma unroll
        for (int j = 0; j < UNROLL; ++j) {
            const int g    = g0 + (m * UNROLL + j) * NTHR;
            const int i    = g << 2;                 // flat pixel index (b*HW + hw)
            const int base = i + (i & ~(HW - 1));    // b*2*HW + hw
            x0[j] = *(const float4*)(pred  + base);
            x1[j] = *(const float4*)(pred  + base + HW);
            t0[j] = *(const float4*)(truth + base);
            t1[j] = *(const float4*)(truth + base + HW);
            mk[j] = *(const float4*)(mask  + i);
            sc[j] = *(const float4*)(scale + i);
        }
        // ---- Phase 2: consume ----
        #pragma unroll
        for (int j = 0; j < UNROLL; ++j) {
            s1 += elem_loss(x0[j].x, x1[j].x, t0[j].x, t1[j].x);
            s1 += elem_loss(x0[j].y, x1[j].y, t0[j].y, t1[j].y);
            s1 += elem_loss(x0[j].z, x1[j].z, t0[j].z, t1[j].z);
            s1 += elem_loss(x0[j].w, x1[j].w, t0[j].w, t1[j].w);
            s2 += mk[j].x * sc[j].x + mk[j].y * sc[j].y
                + mk[j].z * sc[j].z + mk[j].w * sc[j].w;
        }
    }

    // wave64 shuffle reduction
    #pragma unroll
    for (int off = 32; off > 0; off >>= 1) {
        s1 += __shfl_down(s1, off, 64);
        s2 += __shfl_down(s2, off, 64);
    }

    __shared__ float ls1[4], ls2[4];
    const int lane = threadIdx.x & 63;
    const int wv   = threadIdx.x >> 6;
    if (lane == 0) { ls1[wv] = s1; ls2[wv] = s2; }
    __syncthreads();

    if (threadIdx.x == 0) {
        ws[blockIdx.x]          = ls1[0] + ls1[1] + ls1[2] + ls1[3];
        ws[BLOCKS + blockIdx.x] = ls2[0] + ls2[1] + ls2[2] + ls2[3];
    }
}

__global__ __launch_bounds__(256) void xy_finalize(
    const float* __restrict__ ws, float* __restrict__ out)
{
    float a = 0.0f, b = 0.0f;
    for (int i = threadIdx.x; i < BLOCKS; i += 256) {
        a += ws[i];
        b += ws[BLOCKS + i];
    }
    #pragma unroll
    for (int off = 32; off > 0; off >>= 1) {
        a += __shfl_down(a, off, 64);
        b += __shfl_down(b, off, 64);
    }
    __shared__ float la[4], lb[4];
    const int lane = threadIdx.x & 63;
    const int wv   = threadIdx.x >> 6;
    if (lane == 0) { la[wv] = a; lb[wv] = b; }
    __syncthreads();
    if (threadIdx.x == 0) {
        float s1 = la[0] + la[1] + la[2] + la[3];
        float s2 = lb[0] + lb[1] + lb[2] + lb[3];
        out[0] = s1 * s2 * (1.0f / (float)NPIX);
    }
}

extern "C" void kernel_launch(void* const* d_in, const int* in_sizes, int n_in,
                              void* d_out, int out_size, void* d_ws, size_t ws_size,
                              hipStream_t stream) {
    const float* mask  = (const float*)d_in[0];  // object_mask    [16,1,1024,1024]
    const float* scale = (const float*)d_in[1];  // box_loss_scale [16,1,1024,1024]
    const float* pred  = (const float*)d_in[2];  // predict_xy     [16,2,1024,1024]
    const float* truth = (const float*)d_in[3];  // true_xy        [16,2,1024,1024]
    float* out = (float*)d_out;
    float* ws  = (float*)d_ws;                   // block partials (written before read)

    xy_loss_main<<<BLOCKS, THREADS, 0, stream>>>(mask, scale, pred, truth, ws);
    xy_finalize<<<1, 256, 0, stream>>>(ws, out);
}

// Round 4
// 353.557 us; speedup vs baseline: 1.0358x; 1.0068x over previous
//
#include <hip/hip_runtime.h>
#include <math.h>

// Problem constants (B=16, C=2, H=1024, W=1024)
#define HW   (1024 * 1024)          // H*W = 1M (power of two)
#define NPIX (16 * HW)              // B*H*W = 16,777,216
#define NGRP (NPIX / 4)             // float4 groups over pixel space = 4,194,304

constexpr int THREADS = 256;
constexpr int BLOCKS  = 1024;                 // 4 blocks/CU x 256 CUs -> 16 waves/CU at VGPR<=128
constexpr int NTHR    = THREADS * BLOCKS;     // 262,144
constexpr int GPT     = NGRP / NTHR;          // 16 groups per thread
constexpr int UNROLL  = 4;                    // groups batched per macro-iteration (24 loads)
constexpr int MACRO   = GPT / UNROLL;         // 4 macro-iterations
static_assert(GPT * NTHR == NGRP, "exact tiling");
static_assert(MACRO * UNROLL == GPT, "exact unroll");

__device__ __forceinline__ float fast_sigmoid(float x) {
    return __builtin_amdgcn_rcpf(1.0f + __expf(-x));
}

__device__ __forceinline__ float elem_loss(float x0, float x1, float t0, float t1) {
    float p0 = fast_sigmoid(x0);
    float p1 = fast_sigmoid(x1);
    // p0,p1 in (0,1): e^p in (1,e), no stabilization needed
    float lse = __logf(__expf(p0) + __expf(p1));
    return (t0 + t1) * lse - (t0 * p0 + t1 * p1);
}

__global__ __launch_bounds__(THREADS, 4) void xy_loss_main(
    const float* __restrict__ mask,   // [B,1,H,W]
    const float* __restrict__ scale,  // [B,1,H,W]
    const float* __restrict__ pred,   // [B,2,H,W]
    const float* __restrict__ truth,  // [B,2,H,W]
    float* __restrict__ ws)           // [0..BLOCKS): S1 parts, [BLOCKS..2*BLOCKS): S2 parts
{
    const int g0 = blockIdx.x * THREADS + threadIdx.x;

    float s1 = 0.0f, s2 = 0.0f;

    #pragma unroll
    for (int m = 0; m < MACRO; ++m) {
        // ---- Phase 1: issue ALL 24 global_load_dwordx4 for this batch ----
        float4 x0[UNROLL], x1[UNROLL], t0[UNROLL], t1[UNROLL], mk[UNROLL], sc[UNROLL];
        #pragma unroll
        for (int j = 0; j < UNROLL; ++j) {
            const int g    = g0 + (m * UNROLL + j) * NTHR;
            const int i    = g << 2;                 // flat pixel index (b*HW + hw)
            const int base = i + (i & ~(HW - 1));    // b*2*HW + hw
            x0[j] = *(const float4*)(pred  + base);
            x1[j] = *(const float4*)(pred  + base + HW);
            t0[j] = *(const float4*)(truth + base);
            t1[j] = *(const float4*)(truth + base + HW);
            mk[j] = *(const float4*)(mask  + i);
            sc[j] = *(const float4*)(scale + i);
        }

        // Hard scheduling fence: nothing crosses. Forces all 24 loads to be
        // issued before any compute of this batch (defeats the max-occupancy
        // scheduler's load-sinking that kept VGPR=32 in R2/R3).
        __builtin_amdgcn_sched_barrier(0);

        // ---- Phase 2: consume in order (progressive vmcnt drain) ----
        #pragma unroll
        for (int j = 0; j < UNROLL; ++j) {
            s1 += elem_loss(x0[j].x, x1[j].x, t0[j].x, t1[j].x);
            s1 += elem_loss(x0[j].y, x1[j].y, t0[j].y, t1[j].y);
            s1 += elem_loss(x0[j].z, x1[j].z, t0[j].z, t1[j].z);
            s1 += elem_loss(x0[j].w, x1[j].w, t0[j].w, t1[j].w);
            s2 += mk[j].x * sc[j].x + mk[j].y * sc[j].y
                + mk[j].z * sc[j].z + mk[j].w * sc[j].w;
        }
    }

    // wave64 shuffle reduction
    #pragma unroll
    for (int off = 32; off > 0; off >>= 1) {
        s1 += __shfl_down(s1, off, 64);
        s2 += __shfl_down(s2, off, 64);
    }

    __shared__ float ls1[4], ls2[4];
    const int lane = threadIdx.x & 63;
    const int wv   = threadIdx.x >> 6;
    if (lane == 0) { ls1[wv] = s1; ls2[wv] = s2; }
    __syncthreads();

    if (threadIdx.x == 0) {
        ws[blockIdx.x]          = ls1[0] + ls1[1] + ls1[2] + ls1[3];
        ws[BLOCKS + blockIdx.x] = ls2[0] + ls2[1] + ls2[2] + ls2[3];
    }
}

__global__ __launch_bounds__(256) void xy_finalize(
    const float* __restrict__ ws, float* __restrict__ out)
{
    float a = 0.0f, b = 0.0f;
    for (int i = threadIdx.x; i < BLOCKS; i += 256) {
        a += ws[i];
        b += ws[BLOCKS + i];
    }
    #pragma unroll
    for (int off = 32; off > 0; off >>= 1) {
        a += __shfl_down(a, off, 64);
        b += __shfl_down(b, off, 64);
    }
    __shared__ float la[4], lb[4];
    const int lane = threadIdx.x & 63;
    const int wv   = threadIdx.x >> 6;
    if (lane == 0) { la[wv] = a; lb[wv] = b; }
    __syncthreads();
    if (threadIdx.x == 0) {
        float s1 = la[0] + la[1] + la[2] + la[3];
        float s2 = lb[0] + lb[1] + lb[2] + lb[3];
        out[0] = s1 * s2 * (1.0f / (float)NPIX);
    }
}

extern "C" void kernel_launch(void* const* d_in, const int* in_sizes, int n_in,
                              void* d_out, int out_size, void* d_ws, size_t ws_size,
                              hipStream_t stream) {
    const float* mask  = (const float*)d_in[0];  // object_mask    [16,1,1024,1024]
    const float* scale = (const float*)d_in[1];  // box_loss_scale [16,1,1024,1024]
    const float* pred  = (const float*)d_in[2];  // predict_xy     [16,2,1024,1024]
    const float* truth = (const float*)d_in[3];  // true_xy        [16,2,1024,1024]
    float* out = (float*)d_out;
    float* ws  = (float*)d_ws;                   // block partials (written before read)

    xy_loss_main<<<BLOCKS, THREADS, 0, stream>>>(mask, scale, pred, truth, ws);
    xy_finalize<<<1, 256, 0, stream>>>(ws, out);
}

// Round 5
// 348.854 us; speedup vs baseline: 1.0497x; 1.0135x over previous
//
#include <hip/hip_runtime.h>
#include <math.h>

// Problem constants (B=16, C=2, H=1024, W=1024)
#define HW   (1024 * 1024)          // H*W = 1M (power of two)
#define NPIX (16 * HW)              // B*H*W = 16,777,216
#define NGRP (NPIX / 4)             // float4 groups over pixel space = 4,194,304

constexpr int THREADS = 256;
constexpr int NBLK    = NGRP / THREADS;   // 16384 blocks, ONE float4-group per thread
static_assert(NBLK * THREADS == NGRP, "exact tiling");

__device__ __forceinline__ float fast_sigmoid(float x) {
    return __builtin_amdgcn_rcpf(1.0f + __expf(-x));
}

__device__ __forceinline__ float elem_loss(float x0, float x1, float t0, float t1) {
    float p0 = fast_sigmoid(x0);
    float p1 = fast_sigmoid(x1);
    // p0,p1 in (0,1): e^p in (1,e), no stabilization needed
    float lse = __logf(__expf(p0) + __expf(p1));
    return (t0 + t1) * lse - (t0 * p0 + t1 * p1);
}

// No loop: each thread handles exactly one float4 pixel-group. All MLP comes
// from TLP (32 waves/CU at VGPR<=64). Nothing for the loop scheduler to
// serialize — the 6 loads are straight-line and independent.
__global__ __launch_bounds__(THREADS, 8) void xy_loss_main(
    const float* __restrict__ mask,   // [B,1,H,W]
    const float* __restrict__ scale,  // [B,1,H,W]
    const float* __restrict__ pred,   // [B,2,H,W]
    const float* __restrict__ truth,  // [B,2,H,W]
    float* __restrict__ ws)           // [0..NBLK): S1 parts, [NBLK..2*NBLK): S2 parts
{
    const int g    = blockIdx.x * THREADS + threadIdx.x;
    const int i    = g << 2;                 // flat pixel index (b*HW + hw)
    const int base = i + (i & ~(HW - 1));    // b*2*HW + hw

    const float4 x0 = *(const float4*)(pred  + base);
    const float4 x1 = *(const float4*)(pred  + base + HW);
    const float4 t0 = *(const float4*)(truth + base);
    const float4 t1 = *(const float4*)(truth + base + HW);
    const float4 mk = *(const float4*)(mask  + i);
    const float4 sc = *(const float4*)(scale + i);

    float s1 = elem_loss(x0.x, x1.x, t0.x, t1.x)
             + elem_loss(x0.y, x1.y, t0.y, t1.y)
             + elem_loss(x0.z, x1.z, t0.z, t1.z)
             + elem_loss(x0.w, x1.w, t0.w, t1.w);
    float s2 = mk.x * sc.x + mk.y * sc.y + mk.z * sc.z + mk.w * sc.w;

    // wave64 shuffle reduction
    #pragma unroll
    for (int off = 32; off > 0; off >>= 1) {
        s1 += __shfl_down(s1, off, 64);
        s2 += __shfl_down(s2, off, 64);
    }

    __shared__ float ls1[4], ls2[4];
    const int lane = threadIdx.x & 63;
    const int wv   = threadIdx.x >> 6;
    if (lane == 0) { ls1[wv] = s1; ls2[wv] = s2; }
    __syncthreads();

    if (threadIdx.x == 0) {
        ws[blockIdx.x]        = ls1[0] + ls1[1] + ls1[2] + ls1[3];
        ws[NBLK + blockIdx.x] = ls2[0] + ls2[1] + ls2[2] + ls2[3];
    }
}

__global__ __launch_bounds__(1024) void xy_finalize(
    const float* __restrict__ ws, float* __restrict__ out)
{
    float a = 0.0f, b = 0.0f;
    #pragma unroll
    for (int k = 0; k < NBLK / 1024; ++k) {          // 16 entries per thread
        const int i = threadIdx.x + k * 1024;
        a += ws[i];
        b += ws[NBLK + i];
    }
    #pragma unroll
    for (int off = 32; off > 0; off >>= 1) {
        a += __shfl_down(a, off, 64);
        b += __shfl_down(b, off, 64);
    }
    __shared__ float la[16], lb[16];
    const int lane = threadIdx.x & 63;
    const int wv   = threadIdx.x >> 6;
    if (lane == 0) { la[wv] = a; lb[wv] = b; }
    __syncthreads();
    if (threadIdx.x == 0) {
        float s1 = 0.0f, s2 = 0.0f;
        #pragma unroll
        for (int w = 0; w < 16; ++w) { s1 += la[w]; s2 += lb[w]; }
        out[0] = s1 * s2 * (1.0f / (float)NPIX);
    }
}

extern "C" void kernel_launch(void* const* d_in, const int* in_sizes, int n_in,
                              void* d_out, int out_size, void* d_ws, size_t ws_size,
                              hipStream_t stream) {
    const float* mask  = (const float*)d_in[0];  // object_mask    [16,1,1024,1024]
    const float* scale = (const float*)d_in[1];  // box_loss_scale [16,1,1024,1024]
    const float* pred  = (const float*)d_in[2];  // predict_xy     [16,2,1024,1024]
    const float* truth = (const float*)d_in[3];  // true_xy        [16,2,1024,1024]
    float* out = (float*)d_out;
    float* ws  = (float*)d_ws;                   // 2*NBLK floats = 128 KB of partials

    xy_loss_main<<<NBLK, THREADS, 0, stream>>>(mask, scale, pred, truth, ws);
    xy_finalize<<<1, 1024, 0, stream>>>(ws, out);
}